// Round 16
// baseline (273.656 us; speedup 1.0000x reference)
//
#include <hip/hip_runtime.h>
#include <math.h>

// GAT aggregator: embed-gather -> GAT layer1 -> GAT layer2 -> per-graph max pool.
// feat GEMM via bf16 MFMA with el/er folded in as extra output columns;
// edge softmax weights computed INSIDE gather (wave-parallel, LDS-staged);
// CSR build: hist+rank fused with layer-1 feat (atomic latency hidden under
// MFMA); scatter is atomic-free (pos = rowptr[dst]+rank) and XCD-partitioned.

#define HEADS 3
#define HD 64
#define FDIM (HEADS*HD)   // 192
#define NCOL 208          // 192 feat cols + 6 el/er cols + pad
#define NUM_GRAPHS 10
#define NPB 32            // nodes per feat block
#define FROWB 384         // feat row bytes: 64*4 (h0|h1 dwords) + 64*2 (h2)
#define ECHUNK 1024       // edges per scatter block (4 x 256)

typedef short bf16x8 __attribute__((ext_vector_type(8)));
typedef float f32x4  __attribute__((ext_vector_type(4)));

// ---------------- bf16 helpers ----------------
__device__ __forceinline__ float bf2f(unsigned short u) {
    return __uint_as_float(((unsigned int)u) << 16);
}
__device__ __forceinline__ unsigned short f2bf(float f) {
    unsigned int u = __float_as_uint(f);
    unsigned int r = (u + 0x7FFFu + ((u >> 16) & 1u)) >> 16;  // RNE
    return (unsigned short)r;
}

// ---------------- wave helpers ----------------
__device__ __forceinline__ int wave_incl_scan(int v, int lane) {
#pragma unroll
    for (int off = 1; off < 64; off <<= 1) {
        int t = __shfl_up(v, off);
        if (lane >= off) v += t;
    }
    return v;
}

__device__ __forceinline__ unsigned int fmap(float f) {
    unsigned int u = __float_as_uint(f);
    return (u & 0x80000000u) ? ~u : (u | 0x80000000u);
}
__device__ __forceinline__ float funmap(unsigned int u) {
    u = (u & 0x80000000u) ? (u & 0x7FFFFFFFu) : ~u;
    return __uint_as_float(u);
}

// ---------------- prep: Wt (bf16, transposed, +Wl/Wr cols), init gm ----------
__global__ void k_prep(const float* __restrict__ W1, const float* __restrict__ al1,
                       const float* __restrict__ ar1,
                       const float* __restrict__ W2, const float* __restrict__ al2,
                       const float* __restrict__ ar2,
                       unsigned short* __restrict__ Wt1, unsigned short* __restrict__ Wt2,
                       unsigned int* __restrict__ gm) {
    int i = blockIdx.x * blockDim.x + threadIdx.x;
    if (i < 2 * NCOL * HD) {
        int l = i / (NCOL * HD), j = i % (NCOL * HD);
        int c = j >> 6, k = j & 63;
        const float* W  = l ? W2  : W1;
        const float* al = l ? al2 : al1;
        const float* ar = l ? ar2 : ar1;
        unsigned short* Wt = l ? Wt2 : Wt1;
        float v = 0.f;
        if (c < FDIM) {
            v = W[k * FDIM + c];
        } else if (c < FDIM + 6) {
            int h = c - FDIM;
            const float* a = (h < 3) ? al : ar;
            int hh = (h < 3) ? h : h - 3;
            float s = 0.f;
            for (int d = 0; d < HD; ++d)
                s += W[k * FDIM + hh * HD + d] * a[hh * HD + d];
            v = s;
        }
        Wt[j] = f2bf(v);
    }
    if (i < NUM_GRAPHS * HD) gm[i] = 0x007FFFFFu; // fmap(-inf)
}

// ---------------- CSR scans ----------------
__global__ void k_scan1(const int* __restrict__ deg, int* __restrict__ tmp,
                        int* __restrict__ partials, int N) {
    int t = threadIdx.x, b = blockIdx.x;
    int i = b * 256 + t;
    int v = (i < N) ? deg[i] : 0;
    int lane = t & 63, w = t >> 6;
    int incl = wave_incl_scan(v, lane);
    __shared__ int wsum[4];
    if (lane == 63) wsum[w] = incl;
    __syncthreads();
    int off = 0;
    for (int j = 0; j < w; ++j) off += wsum[j];
    incl += off;
    if (i < N) tmp[i] = incl;
    if (t == 255) partials[b] = incl;
}

__global__ void k_scan2(int* __restrict__ partials, int nb) {
    int t = threadIdx.x;                   // 512 threads, nb <= 512
    int v = (t < nb) ? partials[t] : 0;
    int lane = t & 63, w = t >> 6;
    int incl = wave_incl_scan(v, lane);
    __shared__ int wsum[8];
    if (lane == 63) wsum[w] = incl;
    __syncthreads();
    int off = 0;
    for (int j = 0; j < w; ++j) off += wsum[j];
    incl += off;
    if (t < nb) partials[t] = incl;
}

__global__ void k_scan3(const int* __restrict__ tmp, const int* __restrict__ deg,
                        const int* __restrict__ partials, int* __restrict__ rowptr,
                        int N) {
    int i = blockIdx.x * blockDim.x + threadIdx.x;
    if (i >= N) return;
    int b = i >> 8;
    int off = b ? partials[b - 1] : 0;
    int incl = tmp[i] + off;
    rowptr[i + 1] = incl;
    if (i == 0) rowptr[0] = 0;
}

// ---------------- feat body (shared by fused layer-1 and standalone layer-2) --
// featB row (FROWB=384B): [64 x uint (h1<<16|h0)][64 x ushort h2]
__device__ __forceinline__ void feat_body(
        const unsigned short* __restrict__ xbf, const int* __restrict__ ids,
        const float* __restrict__ Wemb, const unsigned short* __restrict__ Wt,
        unsigned char* __restrict__ featB, float4* __restrict__ el4,
        float4* __restrict__ er4, int N, int blk) {
    __shared__ unsigned short xs[NPB][72];    // A tile (bf16), padded
    __shared__ unsigned short ls[NPB][200];   // C tile (bf16), padded
    int t = threadIdx.x;
    int lane = t & 63, w = t >> 6;
    int base = blk * NPB;

    if (ids) {
        for (int i = t; i < NPB * 16; i += 256) {
            int row = i >> 4, c4 = (i & 15) * 4;
            int n = base + row;
            float4 v = {0.f, 0.f, 0.f, 0.f};
            if (n < N) v = *(const float4*)(Wemb + (size_t)ids[n] * HD + c4);
            unsigned short* dp = &xs[row][c4];
            dp[0] = f2bf(v.x); dp[1] = f2bf(v.y); dp[2] = f2bf(v.z); dp[3] = f2bf(v.w);
        }
    } else {
        for (int i = t; i < NPB * 16; i += 256) {
            int row = i >> 4, c4 = (i & 15) * 4;
            int n = base + row;
            ushort4 v = {0, 0, 0, 0};
            if (n < N) v = *(const ushort4*)(xbf + (size_t)n * HD + c4);
            *(ushort4*)(&xs[row][c4]) = v;
        }
    }

    int ntile = (w == 3) ? 4 : 3;
    bf16x8 bfrag[4][2];
#pragma unroll
    for (int c = 0; c < 4; ++c) {
        if (c >= ntile) break;
#pragma unroll
        for (int kk = 0; kk < 2; ++kk) {
            int coln = (w * 3 + c) * 16 + (lane & 15);
            int k0 = kk * 32 + (lane >> 4) * 8;
            bfrag[c][kk] = *(const bf16x8*)(Wt + (size_t)coln * HD + k0);
        }
    }
    __syncthreads();

    f32x4 acc[2][4];
#pragma unroll
    for (int r = 0; r < 2; ++r)
#pragma unroll
        for (int c = 0; c < 4; ++c) acc[r][c] = (f32x4){0.f, 0.f, 0.f, 0.f};
#pragma unroll
    for (int r = 0; r < 2; ++r)
#pragma unroll
        for (int kk = 0; kk < 2; ++kk) {
            int row = r * 16 + (lane & 15);
            int k0 = kk * 32 + (lane >> 4) * 8;
            bf16x8 a = *(const bf16x8*)(&xs[row][k0]);
#pragma unroll
            for (int c = 0; c < 4; ++c) {
                if (c >= ntile) break;
                acc[r][c] = __builtin_amdgcn_mfma_f32_16x16x32_bf16(a, bfrag[c][kk], acc[r][c], 0, 0, 0);
            }
        }

#pragma unroll
    for (int r = 0; r < 2; ++r)
#pragma unroll
        for (int c = 0; c < 3; ++c) {
            int col = (w * 3 + c) * 16 + (lane & 15);
#pragma unroll
            for (int j = 0; j < 4; ++j) {
                int row = r * 16 + (lane >> 4) * 4 + j;
                ls[row][col] = f2bf(acc[r][c][j]);
            }
        }

    if (w == 3) {
        int col = lane & 15;
        if (col < 6) {
#pragma unroll
            for (int r = 0; r < 2; ++r)
#pragma unroll
                for (int j = 0; j < 4; ++j) {
                    int row = r * 16 + (lane >> 4) * 4 + j;
                    int n = base + row;
                    if (n < N) {
                        float v = acc[r][3][j];
                        if (col < 3) ((float*)&el4[n])[col] = v;
                        else         ((float*)&er4[n])[col - 3] = v;
                    }
                }
        }
    }
    __syncthreads();

    // packed feat store: h0|h1 dwords then h2 ushort-pairs
    for (int i = t; i < NPB * 64; i += 256) {
        int row = i >> 6, d = i & 63;
        int n = base + row;
        if (n < N) {
            unsigned int u = ((unsigned int)ls[row][64 + d] << 16) | (unsigned int)ls[row][d];
            *(unsigned int*)(featB + (size_t)n * FROWB + d * 4) = u;
        }
    }
    for (int i = t; i < NPB * 32; i += 256) {
        int row = i >> 5, dd = (i & 31) * 2;
        int n = base + row;
        if (n < N) {
            unsigned int u = (unsigned int)ls[row][128 + dd] |
                             ((unsigned int)ls[row][128 + dd + 1] << 16);
            *(unsigned int*)(featB + (size_t)n * FROWB + 256 + dd * 2) = u;
        }
    }
}

// ---------------- standalone feat (layer 2) ----------------
__global__ __launch_bounds__(256) void k_feat_mfma(
        const unsigned short* __restrict__ xbf, const int* __restrict__ ids,
        const float* __restrict__ Wemb, const unsigned short* __restrict__ Wt,
        unsigned char* __restrict__ featB, float4* __restrict__ el4,
        float4* __restrict__ er4, int N) {
    feat_body(xbf, ids, Wemb, Wt, featB, el4, er4, N, blockIdx.x);
}

// ---------------- fused: hist+rank (latency-bound) + layer-1 feat (MFMA) -----
// hist blocks first: the 1M random atomicAdd round-trips hide under the feat
// blocks' MFMA compute filling the rest of the machine.
__global__ __launch_bounds__(256) void k_hist_feat1(
        const int* __restrict__ dst, int* __restrict__ deg,
        int* __restrict__ rank, int E, int nh,
        const int* __restrict__ ids, const float* __restrict__ Wemb,
        const unsigned short* __restrict__ Wt,
        unsigned char* __restrict__ featB, float4* __restrict__ el4,
        float4* __restrict__ er4, int N) {
    if ((int)blockIdx.x < nh) {
        int i = blockIdx.x * 256 + (int)threadIdx.x;
        if (i < E) {
            int r = atomicAdd(&deg[dst[i]], 1);
            rank[i] = r;
        }
    } else {
        int fb = blockIdx.x - nh;
        if (fb * NPB < N)
            feat_body(nullptr, ids, Wemb, Wt, featB, el4, er4, N, fb);
    }
}

// ---------------- atomic-free XCD-partitioned scatter ----------------
// block s: edge chunk s>>3, commits only dst in range (s&7);
// pos = rowptr[dst] + rank (no atomics). Round-robin block->XCD keeps the
// csrc window XCD-L2-local; correctness independent of the mapping.
__global__ __launch_bounds__(256) void k_scatter(
        const int* __restrict__ src, const int* __restrict__ dst,
        const int* __restrict__ rank, const int* __restrict__ rowptr,
        int* __restrict__ csrc, int E, int NS8) {
    int s = blockIdx.x;
    int lo = (s & 7) * NS8;
    int hi = lo + NS8;
    int i0 = (s >> 3) * ECHUNK + (int)threadIdx.x;
#pragma unroll
    for (int j = 0; j < ECHUNK / 256; ++j) {
        int i = i0 + j * 256;
        if (i < E) {
            int d = dst[i];
            if (d >= lo && d < hi) {
                int pos = rowptr[d] + rank[i];
                csrc[pos] = src[i];
            }
        }
    }
}

// ---------------- gather: fused edge-weight + aggregation ----------------
__global__ void k_gather(const int* __restrict__ rowptr, const int* __restrict__ csrc,
                         const float4* __restrict__ el4, const float4* __restrict__ er4,
                         const unsigned char* __restrict__ featB,
                         const float* __restrict__ b,
                         unsigned short* __restrict__ xout, int N) {
    __shared__ float4 stage[4][64];
    int wid = (blockIdx.x * blockDim.x + threadIdx.x) >> 6; // node
    int lane = threadIdx.x & 63, w = (threadIdx.x >> 6) & 3;
    if (wid >= N) return;
    int beg = rowptr[wid], end = rowptr[wid + 1];
    int deg = end - beg;
    float4 er = er4[wid];
    float acc0 = 0.f, acc1 = 0.f, acc2 = 0.f;
    float ds0 = 0.f, ds1 = 0.f, ds2 = 0.f;
    for (int cb = 0; cb < deg; cb += 64) {
        int nch = min(64, deg - cb);
        if (lane < nch) {
            int s = csrc[beg + cb + lane];
            float4 l = el4[s];
            float e0 = l.x + er.x; e0 = e0 >= 0.f ? e0 : 0.2f * e0;
            float e1 = l.y + er.y; e1 = e1 >= 0.f ? e1 : 0.2f * e1;
            float e2 = l.z + er.z; e2 = e2 >= 0.f ? e2 : 0.2f * e2;
            float4 o;
            o.x = __int_as_float(s);
            o.y = __expf(e0); o.z = __expf(e1); o.w = __expf(e2);
            stage[w][lane] = o;
        }
        __builtin_amdgcn_wave_barrier();
#pragma unroll 4
        for (int j = 0; j < nch; ++j) {
            float4 e = stage[w][j];
            int s = __float_as_int(e.x);
            const unsigned char* frow = featB + (size_t)s * FROWB;
            unsigned int u01 = *(const unsigned int*)(frow + (size_t)lane * 4);
            unsigned short h2 = *(const unsigned short*)(frow + 256 + (size_t)lane * 2);
            float f0 = __uint_as_float(u01 << 16);
            float f1 = __uint_as_float(u01 & 0xffff0000u);
            acc0 = fmaf(e.y, f0, acc0);
            acc1 = fmaf(e.z, f1, acc1);
            acc2 = fmaf(e.w, bf2f(h2), acc2);
            ds0 += e.y; ds1 += e.z; ds2 += e.w;
        }
        __builtin_amdgcn_wave_barrier();
    }
    float o = (acc0 / fmaxf(ds0, 1e-9f) + b[lane])
            + (acc1 / fmaxf(ds1, 1e-9f) + b[HD + lane])
            + (acc2 / fmaxf(ds2, 1e-9f) + b[2 * HD + lane]);
    xout[(size_t)wid * HD + lane] = f2bf(o * (1.f / 3.f));
}

// ---------------- per-graph max pooling (bf16 input) ----------------
__global__ void k_gmax(const unsigned short* __restrict__ x, const int* __restrict__ gid,
                       unsigned int* __restrict__ gm, int N) {
    int lane = threadIdx.x; // 64 threads, lane = d
    int base = blockIdx.x * 64;
    int endn = min(base + 64, N);
    int cur = -1;
    float m = 0.f;
    for (int n = base; n < endn; ++n) {
        int g = gid[n];
        float v = bf2f(x[(size_t)n * HD + lane]);
        if (g != cur) {
            if (cur >= 0) atomicMax(&gm[cur * HD + lane], fmap(m));
            cur = g; m = v;
        } else {
            m = fmaxf(m, v);
        }
    }
    if (cur >= 0) atomicMax(&gm[cur * HD + lane], fmap(m));
}

__global__ void k_gmax_final(const unsigned int* __restrict__ gm, float* __restrict__ out) {
    int i = blockIdx.x * blockDim.x + threadIdx.x;
    if (i < NUM_GRAPHS * HD) out[i] = funmap(gm[i]);
}

// ---------------- launch ----------------
extern "C" void kernel_launch(void* const* d_in, const int* in_sizes, int n_in,
                              void* d_out, int out_size, void* d_ws, size_t ws_size,
                              hipStream_t stream) {
    const int*   node_ids = (const int*)d_in[0];
    const int*   edge_src = (const int*)d_in[1];
    const int*   edge_dst = (const int*)d_in[2];
    const int*   gid      = (const int*)d_in[3];
    const float* Wemb     = (const float*)d_in[4];
    const float* W1  = (const float*)d_in[5];
    const float* al1 = (const float*)d_in[6];
    const float* ar1 = (const float*)d_in[7];
    const float* b1  = (const float*)d_in[8];
    const float* W2  = (const float*)d_in[9];
    const float* al2 = (const float*)d_in[10];
    const float* ar2 = (const float*)d_in[11];
    const float* b2  = (const float*)d_in[12];

    int N = in_sizes[0];
    int E = in_sizes[1];

    char* p = (char*)d_ws;
    auto alloc = [&](size_t bytes) {
        char* r = p;
        p += (bytes + 255) & ~(size_t)255;
        return (void*)r;
    };
    int*   deg      = (int*)alloc((size_t)N * 4);
    int*   tmp      = (int*)alloc((size_t)N * 4);
    int*   partials = (int*)alloc(512 * 4);
    int*   rowptr   = (int*)alloc((size_t)(N + 1) * 4);
    int*   rank     = (int*)alloc((size_t)E * 4);
    int*   csrc     = (int*)alloc((size_t)E * 4);
    unsigned char* featB = (unsigned char*)alloc((size_t)N * FROWB);
    unsigned short* Wt1  = (unsigned short*)alloc((size_t)NCOL * HD * 2);
    unsigned short* Wt2  = (unsigned short*)alloc((size_t)NCOL * HD * 2);
    float4* el4     = (float4*)alloc((size_t)N * 16);
    float4* er4     = (float4*)alloc((size_t)N * 16);
    unsigned short* x1b = (unsigned short*)alloc((size_t)N * HD * 2);
    unsigned int* gm = (unsigned int*)alloc(NUM_GRAPHS * HD * 4);
    (void)ws_size;

    int nb = (N + 255) / 256;
    int nf = (N + NPB - 1) / NPB;
    int nh = (E + 255) / 256;

    hipMemsetAsync(deg, 0, (size_t)N * 4, stream);
    k_prep<<<dim3((2 * NCOL * HD + 255) / 256), dim3(256), 0, stream>>>(
        W1, al1, ar1, W2, al2, ar2, Wt1, Wt2, gm);

    // ---- fused hist+rank (latency) + layer-1 feat (MFMA) ----
    k_hist_feat1<<<dim3(nh + nf), dim3(256), 0, stream>>>(
        edge_dst, deg, rank, E, nh,
        node_ids, Wemb, Wt1, featB, el4, er4, N);

    k_scan1<<<dim3(nb), dim3(256), 0, stream>>>(deg, tmp, partials, N);
    k_scan2<<<dim3(1), dim3(512), 0, stream>>>(partials, nb);
    k_scan3<<<dim3(nb), dim3(256), 0, stream>>>(tmp, deg, partials, rowptr, N);

    // ---- atomic-free XCD-partitioned scatter ----
    int nchunks = (E + ECHUNK - 1) / ECHUNK;
    int NS8 = (N + 7) / 8;
    k_scatter<<<dim3(nchunks * 8), dim3(256), 0, stream>>>(
        edge_src, edge_dst, rank, rowptr, csrc, E, NS8);

    dim3 featGrid(nf), featBlk(256);
    dim3 aggGrid((N * 64 + 255) / 256), aggBlk(256);

    // ---- layer 1 gather ----
    k_gather<<<aggGrid, aggBlk, 0, stream>>>(rowptr, csrc, el4, er4, featB, b1, x1b, N);

    // ---- layer 2 ----
    k_feat_mfma<<<featGrid, featBlk, 0, stream>>>(x1b, nullptr, nullptr, Wt2,
                                                  featB, el4, er4, N);
    k_gather<<<aggGrid, aggBlk, 0, stream>>>(rowptr, csrc, el4, er4, featB, b2, x1b, N);

    // ---- per-graph max pooling ----
    k_gmax<<<dim3((N + 63) / 64), dim3(64), 0, stream>>>(x1b, gid, gm, N);
    k_gmax_final<<<dim3(1), dim3(NUM_GRAPHS * HD), 0, stream>>>(gm, (float*)d_out);
}

// Round 17
// 270.302 us; speedup vs baseline: 1.0124x; 1.0124x over previous
//
#include <hip/hip_runtime.h>
#include <math.h>

// GAT aggregator: embed-gather -> GAT layer1 -> GAT layer2 -> per-graph max pool.
// feat GEMM via bf16 MFMA with el/er folded in as extra output columns;
// edge softmax weights computed INSIDE gather (wave-parallel, LDS-staged);
// CSR scatter is ATOMIC-FREE: hist stores each edge's within-node rank
// (atomicAdd return), scatter computes pos = rowptr[dst]+rank. Scatter is
// XCD-range-partitioned (blockIdx%8) and fused with layer-1 feat.
// [R15 configuration — measured best: 270.8 us]

#define HEADS 3
#define HD 64
#define FDIM (HEADS*HD)   // 192
#define NCOL 208          // 192 feat cols + 6 el/er cols + pad
#define NUM_GRAPHS 10
#define NPB 32            // nodes per feat block
#define FROWB 384         // feat row bytes: 64*4 (h0|h1 dwords) + 64*2 (h2)
#define PREPB 104         // blocks covering 2*NCOL*HD prep elements
#define ECHUNK 1024       // edges per scatter block (4 x 256)

typedef short bf16x8 __attribute__((ext_vector_type(8)));
typedef float f32x4  __attribute__((ext_vector_type(4)));

// ---------------- bf16 helpers ----------------
__device__ __forceinline__ float bf2f(unsigned short u) {
    return __uint_as_float(((unsigned int)u) << 16);
}
__device__ __forceinline__ unsigned short f2bf(float f) {
    unsigned int u = __float_as_uint(f);
    unsigned int r = (u + 0x7FFFu + ((u >> 16) & 1u)) >> 16;  // RNE
    return (unsigned short)r;
}

// ---------------- wave helpers ----------------
__device__ __forceinline__ int wave_incl_scan(int v, int lane) {
#pragma unroll
    for (int off = 1; off < 64; off <<= 1) {
        int t = __shfl_up(v, off);
        if (lane >= off) v += t;
    }
    return v;
}

__device__ __forceinline__ unsigned int fmap(float f) {
    unsigned int u = __float_as_uint(f);
    return (u & 0x80000000u) ? ~u : (u | 0x80000000u);
}
__device__ __forceinline__ float funmap(unsigned int u) {
    u = (u & 0x80000000u) ? (u & 0x7FFFFFFFu) : ~u;
    return __uint_as_float(u);
}

// ---------------- prep (Wt bf16 transposed +Wl/Wr cols, gm init) + hist+rank --
__global__ void k_prep_hist(const float* __restrict__ W1, const float* __restrict__ al1,
                            const float* __restrict__ ar1,
                            const float* __restrict__ W2, const float* __restrict__ al2,
                            const float* __restrict__ ar2,
                            unsigned short* __restrict__ Wt1, unsigned short* __restrict__ Wt2,
                            unsigned int* __restrict__ gm,
                            const int* __restrict__ dst, int* __restrict__ deg,
                            int* __restrict__ rank, int E) {
    if (blockIdx.x < PREPB) {
        int i = blockIdx.x * blockDim.x + threadIdx.x;
        if (i < 2 * NCOL * HD) {
            int l = i / (NCOL * HD), j = i % (NCOL * HD);
            int c = j >> 6, k = j & 63;
            const float* W  = l ? W2  : W1;
            const float* al = l ? al2 : al1;
            const float* ar = l ? ar2 : ar1;
            unsigned short* Wt = l ? Wt2 : Wt1;
            float v = 0.f;
            if (c < FDIM) {
                v = W[k * FDIM + c];
            } else if (c < FDIM + 6) {
                int h = c - FDIM;
                const float* a = (h < 3) ? al : ar;
                int hh = (h < 3) ? h : h - 3;
                float s = 0.f;
                for (int d = 0; d < HD; ++d)
                    s += W[k * FDIM + hh * HD + d] * a[hh * HD + d];
                v = s;
            }
            Wt[j] = f2bf(v);
        }
        if (i < NUM_GRAPHS * HD) gm[i] = 0x007FFFFFu; // fmap(-inf)
    } else {
        int i = (blockIdx.x - PREPB) * blockDim.x + threadIdx.x;
        if (i < E) {
            int r = atomicAdd(&deg[dst[i]], 1);
            rank[i] = r;
        }
    }
}

// ---------------- CSR scans ----------------
__global__ void k_scan1(const int* __restrict__ deg, int* __restrict__ tmp,
                        int* __restrict__ partials, int N) {
    int t = threadIdx.x, b = blockIdx.x;
    int i = b * 256 + t;
    int v = (i < N) ? deg[i] : 0;
    int lane = t & 63, w = t >> 6;
    int incl = wave_incl_scan(v, lane);
    __shared__ int wsum[4];
    if (lane == 63) wsum[w] = incl;
    __syncthreads();
    int off = 0;
    for (int j = 0; j < w; ++j) off += wsum[j];
    incl += off;
    if (i < N) tmp[i] = incl;
    if (t == 255) partials[b] = incl;
}

__global__ void k_scan2(int* __restrict__ partials, int nb) {
    int t = threadIdx.x;                   // 512 threads, nb <= 512
    int v = (t < nb) ? partials[t] : 0;
    int lane = t & 63, w = t >> 6;
    int incl = wave_incl_scan(v, lane);
    __shared__ int wsum[8];
    if (lane == 63) wsum[w] = incl;
    __syncthreads();
    int off = 0;
    for (int j = 0; j < w; ++j) off += wsum[j];
    incl += off;
    if (t < nb) partials[t] = incl;
}

__global__ void k_scan3(const int* __restrict__ tmp, const int* __restrict__ deg,
                        const int* __restrict__ partials, int* __restrict__ rowptr,
                        int N) {
    int i = blockIdx.x * blockDim.x + threadIdx.x;
    if (i >= N) return;
    int b = i >> 8;
    int off = b ? partials[b - 1] : 0;
    int incl = tmp[i] + off;
    rowptr[i + 1] = incl;
    if (i == 0) rowptr[0] = 0;
}

// ---------------- feat body (shared by fused layer-1 and standalone layer-2) --
// featB row (FROWB=384B): [64 x uint (h1<<16|h0)][64 x ushort h2]
__device__ __forceinline__ void feat_body(
        const unsigned short* __restrict__ xbf, const int* __restrict__ ids,
        const float* __restrict__ Wemb, const unsigned short* __restrict__ Wt,
        unsigned char* __restrict__ featB, float4* __restrict__ el4,
        float4* __restrict__ er4, int N, int blk) {
    __shared__ unsigned short xs[NPB][72];    // A tile (bf16), padded
    __shared__ unsigned short ls[NPB][200];   // C tile (bf16), padded
    int t = threadIdx.x;
    int lane = t & 63, w = t >> 6;
    int base = blk * NPB;

    if (ids) {
        for (int i = t; i < NPB * 16; i += 256) {
            int row = i >> 4, c4 = (i & 15) * 4;
            int n = base + row;
            float4 v = {0.f, 0.f, 0.f, 0.f};
            if (n < N) v = *(const float4*)(Wemb + (size_t)ids[n] * HD + c4);
            unsigned short* dp = &xs[row][c4];
            dp[0] = f2bf(v.x); dp[1] = f2bf(v.y); dp[2] = f2bf(v.z); dp[3] = f2bf(v.w);
        }
    } else {
        for (int i = t; i < NPB * 16; i += 256) {
            int row = i >> 4, c4 = (i & 15) * 4;
            int n = base + row;
            ushort4 v = {0, 0, 0, 0};
            if (n < N) v = *(const ushort4*)(xbf + (size_t)n * HD + c4);
            *(ushort4*)(&xs[row][c4]) = v;
        }
    }

    int ntile = (w == 3) ? 4 : 3;
    bf16x8 bfrag[4][2];
#pragma unroll
    for (int c = 0; c < 4; ++c) {
        if (c >= ntile) break;
#pragma unroll
        for (int kk = 0; kk < 2; ++kk) {
            int coln = (w * 3 + c) * 16 + (lane & 15);
            int k0 = kk * 32 + (lane >> 4) * 8;
            bfrag[c][kk] = *(const bf16x8*)(Wt + (size_t)coln * HD + k0);
        }
    }
    __syncthreads();

    f32x4 acc[2][4];
#pragma unroll
    for (int r = 0; r < 2; ++r)
#pragma unroll
        for (int c = 0; c < 4; ++c) acc[r][c] = (f32x4){0.f, 0.f, 0.f, 0.f};
#pragma unroll
    for (int r = 0; r < 2; ++r)
#pragma unroll
        for (int kk = 0; kk < 2; ++kk) {
            int row = r * 16 + (lane & 15);
            int k0 = kk * 32 + (lane >> 4) * 8;
            bf16x8 a = *(const bf16x8*)(&xs[row][k0]);
#pragma unroll
            for (int c = 0; c < 4; ++c) {
                if (c >= ntile) break;
                acc[r][c] = __builtin_amdgcn_mfma_f32_16x16x32_bf16(a, bfrag[c][kk], acc[r][c], 0, 0, 0);
            }
        }

#pragma unroll
    for (int r = 0; r < 2; ++r)
#pragma unroll
        for (int c = 0; c < 3; ++c) {
            int col = (w * 3 + c) * 16 + (lane & 15);
#pragma unroll
            for (int j = 0; j < 4; ++j) {
                int row = r * 16 + (lane >> 4) * 4 + j;
                ls[row][col] = f2bf(acc[r][c][j]);
            }
        }

    if (w == 3) {
        int col = lane & 15;
        if (col < 6) {
#pragma unroll
            for (int r = 0; r < 2; ++r)
#pragma unroll
                for (int j = 0; j < 4; ++j) {
                    int row = r * 16 + (lane >> 4) * 4 + j;
                    int n = base + row;
                    if (n < N) {
                        float v = acc[r][3][j];
                        if (col < 3) ((float*)&el4[n])[col] = v;
                        else         ((float*)&er4[n])[col - 3] = v;
                    }
                }
        }
    }
    __syncthreads();

    // packed feat store: h0|h1 dwords then h2 ushort-pairs
    for (int i = t; i < NPB * 64; i += 256) {
        int row = i >> 6, d = i & 63;
        int n = base + row;
        if (n < N) {
            unsigned int u = ((unsigned int)ls[row][64 + d] << 16) | (unsigned int)ls[row][d];
            *(unsigned int*)(featB + (size_t)n * FROWB + d * 4) = u;
        }
    }
    for (int i = t; i < NPB * 32; i += 256) {
        int row = i >> 5, dd = (i & 31) * 2;
        int n = base + row;
        if (n < N) {
            unsigned int u = (unsigned int)ls[row][128 + dd] |
                             ((unsigned int)ls[row][128 + dd + 1] << 16);
            *(unsigned int*)(featB + (size_t)n * FROWB + 256 + dd * 2) = u;
        }
    }
}

// ---------------- standalone feat (layer 2) ----------------
__global__ __launch_bounds__(256) void k_feat_mfma(
        const unsigned short* __restrict__ xbf, const int* __restrict__ ids,
        const float* __restrict__ Wemb, const unsigned short* __restrict__ Wt,
        unsigned char* __restrict__ featB, float4* __restrict__ el4,
        float4* __restrict__ er4, int N) {
    feat_body(xbf, ids, Wemb, Wt, featB, el4, er4, N, blockIdx.x);
}

// ---------------- fused: atomic-free XCD-partitioned scatter + layer-1 feat --
// Scatter blocks first: block s handles edge chunk s>>3 and commits ONLY edges
// whose dst is in range (s&7): pos = rowptr[dst] + rank (no atomics).
// With round-robin block->XCD dispatch the csrc window stays XCD-L2-local.
__global__ __launch_bounds__(256) void k_feat1_scatter(
        const int* __restrict__ ids, const float* __restrict__ Wemb,
        const unsigned short* __restrict__ Wt,
        unsigned char* __restrict__ featB, float4* __restrict__ el4,
        float4* __restrict__ er4, int N,
        const int* __restrict__ src, const int* __restrict__ dst,
        const int* __restrict__ rank, const int* __restrict__ rowptr,
        int* __restrict__ csrc, int E, int NS8, int nsc8) {
    if ((int)blockIdx.x < nsc8) {
        int s = blockIdx.x;
        int lo = (s & 7) * NS8;
        int hi = lo + NS8;
        int i0 = (s >> 3) * ECHUNK + (int)threadIdx.x;
#pragma unroll
        for (int j = 0; j < ECHUNK / 256; ++j) {
            int i = i0 + j * 256;
            if (i < E) {
                int d = dst[i];
                if (d >= lo && d < hi) {
                    int pos = rowptr[d] + rank[i];
                    csrc[pos] = src[i];
                }
            }
        }
    } else {
        int fb = blockIdx.x - nsc8;
        if (fb * NPB < N)
            feat_body(nullptr, ids, Wemb, Wt, featB, el4, er4, N, fb);
    }
}

// ---------------- gather: fused edge-weight + aggregation ----------------
__global__ void k_gather(const int* __restrict__ rowptr, const int* __restrict__ csrc,
                         const float4* __restrict__ el4, const float4* __restrict__ er4,
                         const unsigned char* __restrict__ featB,
                         const float* __restrict__ b,
                         unsigned short* __restrict__ xout, int N) {
    __shared__ float4 stage[4][64];
    int wid = (blockIdx.x * blockDim.x + threadIdx.x) >> 6; // node
    int lane = threadIdx.x & 63, w = (threadIdx.x >> 6) & 3;
    if (wid >= N) return;
    int beg = rowptr[wid], end = rowptr[wid + 1];
    int deg = end - beg;
    float4 er = er4[wid];
    float acc0 = 0.f, acc1 = 0.f, acc2 = 0.f;
    float ds0 = 0.f, ds1 = 0.f, ds2 = 0.f;
    for (int cb = 0; cb < deg; cb += 64) {
        int nch = min(64, deg - cb);
        if (lane < nch) {
            int s = csrc[beg + cb + lane];
            float4 l = el4[s];
            float e0 = l.x + er.x; e0 = e0 >= 0.f ? e0 : 0.2f * e0;
            float e1 = l.y + er.y; e1 = e1 >= 0.f ? e1 : 0.2f * e1;
            float e2 = l.z + er.z; e2 = e2 >= 0.f ? e2 : 0.2f * e2;
            float4 o;
            o.x = __int_as_float(s);
            o.y = __expf(e0); o.z = __expf(e1); o.w = __expf(e2);
            stage[w][lane] = o;
        }
        __builtin_amdgcn_wave_barrier();
#pragma unroll 4
        for (int j = 0; j < nch; ++j) {
            float4 e = stage[w][j];
            int s = __float_as_int(e.x);
            const unsigned char* frow = featB + (size_t)s * FROWB;
            unsigned int u01 = *(const unsigned int*)(frow + (size_t)lane * 4);
            unsigned short h2 = *(const unsigned short*)(frow + 256 + (size_t)lane * 2);
            float f0 = __uint_as_float(u01 << 16);
            float f1 = __uint_as_float(u01 & 0xffff0000u);
            acc0 = fmaf(e.y, f0, acc0);
            acc1 = fmaf(e.z, f1, acc1);
            acc2 = fmaf(e.w, bf2f(h2), acc2);
            ds0 += e.y; ds1 += e.z; ds2 += e.w;
        }
        __builtin_amdgcn_wave_barrier();
    }
    float o = (acc0 / fmaxf(ds0, 1e-9f) + b[lane])
            + (acc1 / fmaxf(ds1, 1e-9f) + b[HD + lane])
            + (acc2 / fmaxf(ds2, 1e-9f) + b[2 * HD + lane]);
    xout[(size_t)wid * HD + lane] = f2bf(o * (1.f / 3.f));
}

// ---------------- per-graph max pooling (bf16 input) ----------------
__global__ void k_gmax(const unsigned short* __restrict__ x, const int* __restrict__ gid,
                       unsigned int* __restrict__ gm, int N) {
    int lane = threadIdx.x; // 64 threads, lane = d
    int base = blockIdx.x * 64;
    int endn = min(base + 64, N);
    int cur = -1;
    float m = 0.f;
    for (int n = base; n < endn; ++n) {
        int g = gid[n];
        float v = bf2f(x[(size_t)n * HD + lane]);
        if (g != cur) {
            if (cur >= 0) atomicMax(&gm[cur * HD + lane], fmap(m));
            cur = g; m = v;
        } else {
            m = fmaxf(m, v);
        }
    }
    if (cur >= 0) atomicMax(&gm[cur * HD + lane], fmap(m));
}

__global__ void k_gmax_final(const unsigned int* __restrict__ gm, float* __restrict__ out) {
    int i = blockIdx.x * blockDim.x + threadIdx.x;
    if (i < NUM_GRAPHS * HD) out[i] = funmap(gm[i]);
}

// ---------------- launch ----------------
extern "C" void kernel_launch(void* const* d_in, const int* in_sizes, int n_in,
                              void* d_out, int out_size, void* d_ws, size_t ws_size,
                              hipStream_t stream) {
    const int*   node_ids = (const int*)d_in[0];
    const int*   edge_src = (const int*)d_in[1];
    const int*   edge_dst = (const int*)d_in[2];
    const int*   gid      = (const int*)d_in[3];
    const float* Wemb     = (const float*)d_in[4];
    const float* W1  = (const float*)d_in[5];
    const float* al1 = (const float*)d_in[6];
    const float* ar1 = (const float*)d_in[7];
    const float* b1  = (const float*)d_in[8];
    const float* W2  = (const float*)d_in[9];
    const float* al2 = (const float*)d_in[10];
    const float* ar2 = (const float*)d_in[11];
    const float* b2  = (const float*)d_in[12];

    int N = in_sizes[0];
    int E = in_sizes[1];

    char* p = (char*)d_ws;
    auto alloc = [&](size_t bytes) {
        char* r = p;
        p += (bytes + 255) & ~(size_t)255;
        return (void*)r;
    };
    int*   deg      = (int*)alloc((size_t)N * 4);
    int*   tmp      = (int*)alloc((size_t)N * 4);
    int*   partials = (int*)alloc(512 * 4);
    int*   rowptr   = (int*)alloc((size_t)(N + 1) * 4);
    int*   rank     = (int*)alloc((size_t)E * 4);
    int*   csrc     = (int*)alloc((size_t)E * 4);
    unsigned char* featB = (unsigned char*)alloc((size_t)N * FROWB);
    unsigned short* Wt1  = (unsigned short*)alloc((size_t)NCOL * HD * 2);
    unsigned short* Wt2  = (unsigned short*)alloc((size_t)NCOL * HD * 2);
    float4* el4     = (float4*)alloc((size_t)N * 16);
    float4* er4     = (float4*)alloc((size_t)N * 16);
    unsigned short* x1b = (unsigned short*)alloc((size_t)N * HD * 2);
    unsigned int* gm = (unsigned int*)alloc(NUM_GRAPHS * HD * 4);
    (void)ws_size;

    int nb = (N + 255) / 256;

    hipMemsetAsync(deg, 0, (size_t)N * 4, stream);
    // prep (Wt, gm) + edge-degree histogram with rank capture, one launch
    k_prep_hist<<<dim3(PREPB + (E + 255) / 256), dim3(256), 0, stream>>>(
        W1, al1, ar1, W2, al2, ar2, Wt1, Wt2, gm, edge_dst, deg, rank, E);
    k_scan1<<<dim3(nb), dim3(256), 0, stream>>>(deg, tmp, partials, N);
    k_scan2<<<dim3(1), dim3(512), 0, stream>>>(partials, nb);
    k_scan3<<<dim3(nb), dim3(256), 0, stream>>>(tmp, deg, partials, rowptr, N);

    dim3 featGrid((N + NPB - 1) / NPB), featBlk(256);
    dim3 aggGrid((N * 64 + 255) / 256), aggBlk(256);

    // fused: scatter blocks first (8 ranges x edge chunks), feat blocks after
    int nf = (N + NPB - 1) / NPB;
    int nchunks = (E + ECHUNK - 1) / ECHUNK;
    int nsc8 = nchunks * 8;
    int NS8 = (N + 7) / 8;
    dim3 fusedGrid(nsc8 + nf);

    // ---- layer 1 (atomic-free XCD-partitioned scatter + feat) ----
    k_feat1_scatter<<<fusedGrid, featBlk, 0, stream>>>(
        node_ids, Wemb, Wt1, featB, el4, er4, N,
        edge_src, edge_dst, rank, rowptr, csrc, E, NS8, nsc8);
    k_gather<<<aggGrid, aggBlk, 0, stream>>>(rowptr, csrc, el4, er4, featB, b1, x1b, N);

    // ---- layer 2 ----
    k_feat_mfma<<<featGrid, featBlk, 0, stream>>>(x1b, nullptr, nullptr, Wt2,
                                                  featB, el4, er4, N);
    k_gather<<<aggGrid, aggBlk, 0, stream>>>(rowptr, csrc, el4, er4, featB, b2, x1b, N);

    // ---- per-graph max pooling ----
    k_gmax<<<dim3((N + 63) / 64), dim3(64), 0, stream>>>(x1b, gid, gm, N);
    k_gmax_final<<<dim3(1), dim3(NUM_GRAPHS * HD), 0, stream>>>(gm, (float*)d_out);
}